// Round 7
// baseline (357.452 us; speedup 1.0000x reference)
//
#include <hip/hip_runtime.h>
#include <hip/hip_bf16.h>

#define NEG_ATT 0.2f
#define NEG_ACT 0.01f
#define NAGG 2048      // aggregate_h4 grid (persistent). 6144 (CP rebalancing) WORSE (r5);
                       // dynamic atomic queues dead (~90ns/pop, r4); agg is gather-BW bound (r6).
#define LOG2E 1.4426950408889634f

typedef __attribute__((ext_vector_type(8))) short short8;
typedef __attribute__((ext_vector_type(4))) float f32x4;

__device__ __forceinline__ float b2f(unsigned short h) {
    return __uint_as_float((unsigned int)h << 16);
}
// packed f32x2 -> bf16x2 (RNE), single HW instruction on gfx950
__device__ __forceinline__ unsigned cvt_pk_bf16(float lo, float hi) {
    unsigned r;
    asm("v_cvt_pk_bf16_f32 %0, %1, %2" : "=v"(r) : "v"(lo), "v"(hi));
    return r;
}
__device__ __forceinline__ float fexp2(float x) {
#if __has_builtin(__builtin_amdgcn_exp2f)
    return __builtin_amdgcn_exp2f(x);
#else
    return exp2f(x);
#endif
}

// ---------------- CSR build ----------------

#define SCAN_CHUNK 1024
// deg holds edge-counts only (self-loop added as +1 here)
__global__ void scan1(const int* __restrict__ deg, int* __restrict__ offs,
                      int* blocksum, int Nn) {
    __shared__ int sh[256];
    int b = blockIdx.x, t = threadIdx.x;
    int base = b * SCAN_CHUNK + t * 4;
    int v[4];
    int s = 0;
    for (int j = 0; j < 4; j++) {
        int idx = base + j;
        v[j] = (idx < Nn) ? deg[idx] + 1 : 0;
        s += v[j];
    }
    sh[t] = s;
    __syncthreads();
    for (int off = 1; off < 256; off <<= 1) {
        int x = (t >= off) ? sh[t - off] : 0;
        __syncthreads();
        sh[t] += x;
        __syncthreads();
    }
    int excl = sh[t] - s;
    if (t == 255) blocksum[b] = sh[255];
    int run = excl;
    for (int j = 0; j < 4; j++) {
        int idx = base + j;
        if (idx < Nn) offs[idx] = run;
        run += v[j];
    }
}

// fused scan2+scan3: per-thread prefix over <=G block sums (L2-hot)
__global__ void scan23(int* __restrict__ offs, const int* __restrict__ bsum,
                       int* __restrict__ cursor, int Nn, int G) {
    int i = blockIdx.x * 256 + threadIdx.x;
    if (i > Nn) return;
    int g = i >> 10;
    int basev = 0;
    for (int k = 0; k < g; k++) basev += bsum[k];
    if (i == Nn) {
        int tot = basev;
        for (int k = g; k < G; k++) tot += bsum[k];
        offs[Nn] = tot;
        return;
    }
    int v = offs[i] + basev;
    offs[i] = v;
    cursor[i] = v;
}

__global__ void fill_csr(const int* __restrict__ ei, int* cursor, int* csr, int E, int Nn) {
    int t = blockIdx.x * 256 + threadIdx.x;
    if (t < E) {
        int s = ei[t];
        int d = ei[E + t];
        int p = atomicAdd(&cursor[d], 1);
        csr[p] = s;
    } else if (t < E + Nn) {
        int nn = t - E;
        int p = atomicAdd(&cursor[nn], 1);
        csr[p] = nn;
    }
}

// ------- prep: all fp32->bf16 conversions + edge degree count (deg pre-zeroed) -------

__global__ __launch_bounds__(256) void prep_all(
    int* __restrict__ deg, const int* __restrict__ ei, int E,
    const float* __restrict__ x, unsigned short* __restrict__ xb, int nx, int nxpad,
    const float* __restrict__ w1, unsigned short* __restrict__ o1, int n1,
    const float* __restrict__ w2, unsigned short* __restrict__ o2, int n2,
    const float* __restrict__ w3, unsigned short* __restrict__ o3, int n3) {
    int id = blockIdx.x * 256 + threadIdx.x;
    int nconv = (nxpad + n1 + n2 + n3) / 8;
    if (id >= nconv) {
        int e = id - nconv;
        if (e < E) atomicAdd(&deg[ei[E + e]], 1);
        return;
    }
    int i = id * 8;
    const float* in;
    unsigned short* out;
    if (i < nxpad) {
        if (i >= nx) {
            *(ushort4*)&xb[i] = make_ushort4(0, 0, 0, 0);
            *(ushort4*)&xb[i + 4] = make_ushort4(0, 0, 0, 0);
            return;
        }
        in = x + i; out = xb + i;
    } else {
        int j = i - nxpad;
        if (j < n1) { in = w1 + j; out = o1 + j; }
        else if (j < n1 + n2) { in = w2 + (j - n1); out = o2 + (j - n1); }
        else { in = w3 + (j - n1 - n2); out = o3 + (j - n1 - n2); }
    }
    float4 a = *(const float4*)in;
    float4 b = *(const float4*)(in + 4);
    uint4 o;
    o.x = cvt_pk_bf16(a.x, a.y);
    o.y = cvt_pk_bf16(a.z, a.w);
    o.z = cvt_pk_bf16(b.x, b.y);
    o.w = cvt_pk_bf16(b.z, b.w);
    *(uint4*)out = o;
}

// BN-apply transform: leaky(sc*y+sh) (+res when RES), pack 2 bf16 via cvt_pk
template <bool RES>
__device__ __forceinline__ unsigned bnpack2(unsigned short ya, unsigned short yb_,
                                            float sca, float scb, float sha, float shb,
                                            unsigned short ra, unsigned short rb_) {
    float v0 = sca * b2f(ya) + sha; v0 = v0 > 0.f ? v0 : NEG_ACT * v0;
    float v1 = scb * b2f(yb_) + shb; v1 = v1 > 0.f ? v1 : NEG_ACT * v1;
    if (RES) { v0 += b2f(ra); v1 += b2f(rb_); }
    return cvt_pk_bf16(v0, v1);
}

// ---------------- merged-head MFMA GEMM (TN): BM=64, all 4 heads per block ------
// r7: one block computes the FULL 256-col output of a 64-row m-tile. A panel is
// loaded+BN-transformed ONCE (was 4x across head-blocks). wave w = head w; the
// verified per-wave 16-lane logit reduce is unchanged. als/ald pre-scaled by log2e.

template <int K, bool FUSE, bool FRES, bool FWOUT>
__global__ __launch_bounds__(256) void gemm_h4(
    const unsigned short* __restrict__ Xb, const unsigned short* __restrict__ Wb,
    unsigned short* __restrict__ Hb, const float* __restrict__ a_s,
    const float* __restrict__ a_d, float* __restrict__ als, float* __restrict__ ald,
    const unsigned short* __restrict__ Yb_in, unsigned short* __restrict__ RWbuf,
    const float* __restrict__ scale, const float* __restrict__ shift, int Nn) {
    constexpr int LD = 72;   // ushort pitch for As/Bs
    constexpr int SP = 268;  // float pitch for epilogue staging (268%32=12 -> spread)
    __shared__ __align__(16) char smem[(64 + 256) * LD * 2];  // 46080 B
    unsigned short* As = (unsigned short*)smem;
    unsigned short* Bs = As + 64 * LD;
    int tid = threadIdx.x;
    int hd = tid >> 6;            // wave = head
    int lane = tid & 63;
    int quad = lane >> 4, l16 = lane & 15;
    int m0 = blockIdx.x * 64;
    int arow = tid >> 3;          // 0..31
    int achk = (tid & 7) * 8;
    f32x4 acc[4][4] = {};
    for (int k0 = 0; k0 < K; k0 += 64) {
        __syncthreads();
        if (FUSE) {
            int cb = k0 + achk;
            float4 sc0 = *(const float4*)&scale[cb];
            float4 sc1 = *(const float4*)&scale[cb + 4];
            float4 sh0 = *(const float4*)&shift[cb];
            float4 sh1 = *(const float4*)&shift[cb + 4];
#pragma unroll
            for (int p = 0; p < 2; p++) {
                int r = arow + p * 32;
                int m = m0 + r;
                uint4 o = make_uint4(0, 0, 0, 0);
                if (m < Nn) {
                    ushort4 ua = *(const ushort4*)&Yb_in[(size_t)m * 256 + cb];
                    ushort4 ub = *(const ushort4*)&Yb_in[(size_t)m * 256 + cb + 4];
                    ushort4 ra = make_ushort4(0, 0, 0, 0), rb = ra;
                    if (FRES) {
                        ra = *(const ushort4*)&RWbuf[(size_t)m * 256 + cb];
                        rb = *(const ushort4*)&RWbuf[(size_t)m * 256 + cb + 4];
                    }
                    o.x = bnpack2<FRES>(ua.x, ua.y, sc0.x, sc0.y, sh0.x, sh0.y, ra.x, ra.y);
                    o.y = bnpack2<FRES>(ua.z, ua.w, sc0.z, sc0.w, sh0.z, sh0.w, ra.z, ra.w);
                    o.z = bnpack2<FRES>(ub.x, ub.y, sc1.x, sc1.y, sh1.x, sh1.y, rb.x, rb.y);
                    o.w = bnpack2<FRES>(ub.z, ub.w, sc1.z, sc1.w, sh1.z, sh1.w, rb.z, rb.w);
                    if (FWOUT)
                        *(uint4*)&RWbuf[(size_t)m * 256 + cb] = o;
                }
                *(uint4*)&As[r * LD + achk] = o;
            }
        } else {
#pragma unroll
            for (int p = 0; p < 2; p++) {
                int r = arow + p * 32;
                *(int4*)&As[r * LD + achk] = *(const int4*)&Xb[(size_t)(m0 + r) * K + k0 + achk];
            }
        }
#pragma unroll
        for (int p = 0; p < 8; p++) {
            int r = arow + p * 32;
            *(int4*)&Bs[r * LD + achk] = *(const int4*)&Wb[(size_t)r * K + k0 + achk];
        }
        __syncthreads();
#pragma unroll
        for (int ks = 0; ks < 2; ks++) {
            short8 af[4], bfr[4];
#pragma unroll
            for (int i = 0; i < 4; i++)
                af[i] = *(const short8*)&As[(i * 16 + l16) * LD + ks * 32 + quad * 8];
#pragma unroll
            for (int j = 0; j < 4; j++)
                bfr[j] = *(const short8*)&Bs[(hd * 64 + j * 16 + l16) * LD + ks * 32 + quad * 8];
#pragma unroll
            for (int i = 0; i < 4; i++)
#pragma unroll
                for (int j = 0; j < 4; j++)
                    acc[i][j] = __builtin_amdgcn_mfma_f32_16x16x32_bf16(af[i], bfr[j], acc[i][j], 0, 0, 0);
        }
    }
    __syncthreads();

    // attention logits for this wave's head (cols hd*64..hd*64+63)
    float asv[4], adv[4];
#pragma unroll
    for (int j = 0; j < 4; j++) {
        asv[j] = a_s[hd * 64 + j * 16 + l16] * LOG2E;
        adv[j] = a_d[hd * 64 + j * 16 + l16] * LOG2E;
    }
#pragma unroll
    for (int i = 0; i < 4; i++)
#pragma unroll
        for (int r = 0; r < 4; r++) {
            float ps = acc[i][0][r] * asv[0] + acc[i][1][r] * asv[1] +
                       acc[i][2][r] * asv[2] + acc[i][3][r] * asv[3];
            float pd = acc[i][0][r] * adv[0] + acc[i][1][r] * adv[1] +
                       acc[i][2][r] * adv[2] + acc[i][3][r] * adv[3];
#pragma unroll
            for (int mm = 1; mm < 16; mm <<= 1) {
                ps += __shfl_xor(ps, mm);
                pd += __shfl_xor(pd, mm);
            }
            if (l16 == 0) {
                int m = m0 + i * 16 + quad * 4 + r;
                als[m * 4 + hd] = ps;
                ald[m * 4 + hd] = pd;
            }
        }

    // Hb write: 2 phases of 32 rows via skewed LDS staging (col' = c + c/32)
    float* stg = (float*)smem;
#pragma unroll
    for (int ph = 0; ph < 2; ph++) {
        __syncthreads();
#pragma unroll
        for (int i2 = 0; i2 < 2; i2++) {
            int i = ph * 2 + i2;
#pragma unroll
            for (int j = 0; j < 4; j++) {
                int c = hd * 64 + j * 16 + l16;
                int cs = c + (c >> 5);
#pragma unroll
                for (int r = 0; r < 4; r++)
                    stg[(i2 * 16 + quad * 4 + r) * SP + cs] = acc[i][j][r];
            }
        }
        __syncthreads();
        int row = tid >> 3;
        int cch = (tid & 7) * 32;
        const float4* sp = (const float4*)&stg[row * SP + cch + (cch >> 5)];
        uint4* dst = (uint4*)&Hb[(size_t)(m0 + ph * 32 + row) * 256 + cch];
#pragma unroll
        for (int q = 0; q < 4; q++) {
            float4 va = sp[2 * q], vb = sp[2 * q + 1];
            uint4 o;
            o.x = cvt_pk_bf16(va.x, va.y);
            o.y = cvt_pk_bf16(va.z, va.w);
            o.z = cvt_pk_bf16(vb.x, vb.y);
            o.w = cvt_pk_bf16(vb.z, vb.w);
            dst[q] = o;
        }
    }
}

// ---------------- old per-head GEMM, kept for the HEADS==1 final layer ----------

template <int K, int CO, int HEADS, bool FUSE, bool FRES, bool FWOUT>
__global__ __launch_bounds__(256) void gemm_mfma(
    const unsigned short* __restrict__ Xb, const unsigned short* __restrict__ Wb,
    unsigned short* __restrict__ Hb, const float* __restrict__ a_s,
    const float* __restrict__ a_d, float* __restrict__ als, float* __restrict__ ald,
    const unsigned short* __restrict__ Yb_in, unsigned short* __restrict__ RWbuf,
    const float* __restrict__ scale, const float* __restrict__ shift, int Nn) {
    constexpr int BM = 128, BK = 64, LD = 72, SLD = 68;
    __shared__ __align__(16) char smem[4 * 32 * SLD * 4];
    unsigned short* As = (unsigned short*)smem;
    unsigned short* Bs = As + BM * LD;
    int tid = threadIdx.x;
    int wave = tid >> 6, lane = tid & 63;
    int quad = lane >> 4, l16 = lane & 15;
    int mt = blockIdx.x, hd = 0;
    int m0 = mt * BM, n0 = 0;
    int arow = tid >> 3;
    int achk = (tid & 7) * 8;
    f32x4 acc[2][4] = {};
    for (int k0 = 0; k0 < K; k0 += BK) {
        __syncthreads();
        if (FUSE) {
            int cb = k0 + achk;
            float4 sc0 = *(const float4*)&scale[cb];
            float4 sc1 = *(const float4*)&scale[cb + 4];
            float4 sh0 = *(const float4*)&shift[cb];
            float4 sh1 = *(const float4*)&shift[cb + 4];
#pragma unroll
            for (int p = 0; p < 4; p++) {
                int r = arow + p * 32;
                int m = m0 + r;
                uint4 o = make_uint4(0, 0, 0, 0);
                if (m < Nn) {
                    ushort4 ua = *(const ushort4*)&Yb_in[(size_t)m * 256 + cb];
                    ushort4 ub = *(const ushort4*)&Yb_in[(size_t)m * 256 + cb + 4];
                    ushort4 ra = make_ushort4(0, 0, 0, 0), rb = ra;
                    if (FRES) {
                        ra = *(const ushort4*)&RWbuf[(size_t)m * 256 + cb];
                        rb = *(const ushort4*)&RWbuf[(size_t)m * 256 + cb + 4];
                    }
                    o.x = bnpack2<FRES>(ua.x, ua.y, sc0.x, sc0.y, sh0.x, sh0.y, ra.x, ra.y);
                    o.y = bnpack2<FRES>(ua.z, ua.w, sc0.z, sc0.w, sh0.z, sh0.w, ra.z, ra.w);
                    o.z = bnpack2<FRES>(ub.x, ub.y, sc1.x, sc1.y, sh1.x, sh1.y, rb.x, rb.y);
                    o.w = bnpack2<FRES>(ub.z, ub.w, sc1.z, sc1.w, sh1.z, sh1.w, rb.z, rb.w);
                    if (FWOUT && hd == 0)
                        *(uint4*)&RWbuf[(size_t)m * 256 + cb] = o;
                }
                *(uint4*)&As[r * LD + achk] = o;
            }
        } else {
#pragma unroll
            for (int p = 0; p < 4; p++) {
                int r = arow + p * 32;
                *(int4*)&As[r * LD + achk] = *(const int4*)&Xb[(size_t)(m0 + r) * K + k0 + achk];
            }
        }
#pragma unroll
        for (int p = 0; p < 2; p++) {
            int r = arow + p * 32;
            if (r < CO)
                *(int4*)&Bs[r * LD + achk] = *(const int4*)&Wb[(size_t)(n0 + r) * K + k0 + achk];
        }
        __syncthreads();
#pragma unroll
        for (int ks = 0; ks < 2; ks++) {
            short8 af[2], bfr[4];
#pragma unroll
            for (int i = 0; i < 2; i++)
                af[i] = *(const short8*)&As[(wave * 32 + i * 16 + l16) * LD + ks * 32 + quad * 8];
#pragma unroll
            for (int j = 0; j < 4; j++)
                bfr[j] = *(const short8*)&Bs[(j * 16 + l16) * LD + ks * 32 + quad * 8];
#pragma unroll
            for (int i = 0; i < 2; i++)
#pragma unroll
                for (int j = 0; j < 4; j++)
                    acc[i][j] = __builtin_amdgcn_mfma_f32_16x16x32_bf16(af[i], bfr[j], acc[i][j], 0, 0, 0);
        }
    }
    __syncthreads();

    float asv[4], adv[4];
#pragma unroll
    for (int j = 0; j < 4; j++) {
        asv[j] = a_s[j * 16 + l16] * LOG2E;
        adv[j] = a_d[j * 16 + l16] * LOG2E;
    }
#pragma unroll
    for (int i = 0; i < 2; i++)
#pragma unroll
        for (int r = 0; r < 4; r++) {
            float ps = acc[i][0][r] * asv[0] + acc[i][1][r] * asv[1] +
                       acc[i][2][r] * asv[2] + acc[i][3][r] * asv[3];
            float pd = acc[i][0][r] * adv[0] + acc[i][1][r] * adv[1] +
                       acc[i][2][r] * adv[2] + acc[i][3][r] * adv[3];
#pragma unroll
            for (int mm = 1; mm < 16; mm <<= 1) {
                ps += __shfl_xor(ps, mm);
                pd += __shfl_xor(pd, mm);
            }
            if (l16 == 0) {
                int m = m0 + wave * 32 + i * 16 + quad * 4 + r;
                als[m * HEADS + hd] = ps;
                ald[m * HEADS + hd] = pd;
            }
        }

    float* stg = (float*)smem + wave * 32 * SLD;
#pragma unroll
    for (int i = 0; i < 2; i++)
#pragma unroll
        for (int j = 0; j < 4; j++)
#pragma unroll
            for (int r = 0; r < 4; r++)
                stg[(i * 16 + quad * 4 + r) * SLD + j * 16 + l16] = acc[i][j][r];
    int g = lane >> 3, c8 = (lane & 7) * 8;
#pragma unroll
    for (int p = 0; p < 4; p++) {
        int row = p * 8 + g;
        float4 v0 = *(const float4*)&stg[row * SLD + c8];
        float4 v1 = *(const float4*)&stg[row * SLD + c8 + 4];
        uint4 o;
        o.x = cvt_pk_bf16(v0.x, v0.y);
        o.y = cvt_pk_bf16(v0.z, v0.w);
        o.z = cvt_pk_bf16(v1.x, v1.y);
        o.w = cvt_pk_bf16(v1.z, v1.w);
        *(uint4*)&Hb[(size_t)(m0 + wave * 32 + row) * CO + n0 + c8] = o;
    }
}

// ---------------- edge-softmax aggregation --------------------------------------
// readlane-uniform edge walk; exp2 with log2e pre-folded; leaky = max(x, 0.2x).
// Fused BN sum/sumsq -> per-block partials (plain coalesced stores).

#define EDGE4(J)                                                                     \
    {                                                                                \
        int s0 = __builtin_amdgcn_readlane(idx, (J));                                \
        int s1 = __builtin_amdgcn_readlane(idx, (J) + 1);                            \
        int s2 = __builtin_amdgcn_readlane(idx, (J) + 2);                            \
        int s3 = __builtin_amdgcn_readlane(idx, (J) + 3);                            \
        const unsigned short* r0 = Hb + (size_t)s0 * 256;                            \
        const unsigned short* r1 = Hb + (size_t)s1 * 256;                            \
        const unsigned short* r2 = Hb + (size_t)s2 * 256;                            \
        const unsigned short* r3 = Hb + (size_t)s3 * 256;                            \
        float a0 = als[s0 * 4 + hd], a1 = als[s1 * 4 + hd];                          \
        float a2 = als[s2 * 4 + hd], a3 = als[s3 * 4 + hd];                          \
        ushort4 h0 = *(const ushort4*)&r0[c4];                                       \
        ushort4 h1 = *(const ushort4*)&r1[c4];                                       \
        ushort4 h2 = *(const ushort4*)&r2[c4];                                       \
        ushort4 h3 = *(const ushort4*)&r3[c4];                                       \
        float e0 = a0 + aldn; e0 = fmaxf(e0, NEG_ATT * e0);                          \
        float e1 = a1 + aldn; e1 = fmaxf(e1, NEG_ATT * e1);                          \
        float e2 = a2 + aldn; e2 = fmaxf(e2, NEG_ATT * e2);                          \
        float e3 = a3 + aldn; e3 = fmaxf(e3, NEG_ATT * e3);                          \
        float w0 = fexp2(e0), w1 = fexp2(e1), w2 = fexp2(e2), w3 = fexp2(e3);        \
        den += (w0 + w1) + (w2 + w3);                                                \
        acc.x += w0 * b2f(h0.x) + w1 * b2f(h1.x) + w2 * b2f(h2.x) + w3 * b2f(h3.x);  \
        acc.y += w0 * b2f(h0.y) + w1 * b2f(h1.y) + w2 * b2f(h2.y) + w3 * b2f(h3.y);  \
        acc.z += w0 * b2f(h0.z) + w1 * b2f(h1.z) + w2 * b2f(h2.z) + w3 * b2f(h3.z);  \
        acc.w += w0 * b2f(h0.w) + w1 * b2f(h1.w) + w2 * b2f(h2.w) + w3 * b2f(h3.w);  \
    }

__global__ __launch_bounds__(256) void aggregate_h4(
    const unsigned short* __restrict__ Hb, const float* __restrict__ als,
    const float* __restrict__ ald, const int* __restrict__ offs,
    const int* __restrict__ csr, unsigned short* __restrict__ Yb,
    float* __restrict__ partial, int Nn) {
    __shared__ float red[4 * 512];
    int wave = threadIdx.x >> 6;
    int lane = threadIdx.x & 63;
    int hd = lane >> 4;
    int c4 = lane * 4;
    float4 bs = make_float4(0.f, 0.f, 0.f, 0.f);
    float4 bq = make_float4(0.f, 0.f, 0.f, 0.f);
    for (int n = blockIdx.x * 4 + wave; n < Nn; n += gridDim.x * 4) {
        float aldn = ald[n * 4 + hd];
        int beg = __builtin_amdgcn_readfirstlane(offs[n]);
        int end = __builtin_amdgcn_readfirstlane(offs[n + 1]);
        float4 acc = make_float4(0.f, 0.f, 0.f, 0.f);
        float den = 0.f;
        for (int b = beg; b < end; b += 64) {
            int cnt = min(64, end - b);
            int idx = 0;
            if (lane < cnt) idx = csr[b + lane];
            int j = 0;
            for (; j + 8 <= cnt; j += 8) {
                EDGE4(j);
                EDGE4(j + 4);
            }
            for (; j + 4 <= cnt; j += 4) {
                EDGE4(j);
            }
            for (; j < cnt; j++) {
                int s = __builtin_amdgcn_readlane(idx, j);
                const unsigned short* rr = Hb + (size_t)s * 256;
                float e = als[s * 4 + hd] + aldn;
                e = fmaxf(e, NEG_ATT * e);
                float w = fexp2(e);
                den += w;
                ushort4 hv = *(const ushort4*)&rr[c4];
                acc.x += w * b2f(hv.x); acc.y += w * b2f(hv.y);
                acc.z += w * b2f(hv.z); acc.w += w * b2f(hv.w);
            }
        }
        float inv = 1.f / den;
        float yx = acc.x * inv, yy = acc.y * inv, yz = acc.z * inv, yw = acc.w * inv;
        uint2 o;
        o.x = cvt_pk_bf16(yx, yy);
        o.y = cvt_pk_bf16(yz, yw);
        *(uint2*)&Yb[(size_t)n * 256 + c4] = o;
        bs.x += yx; bs.y += yy; bs.z += yz; bs.w += yw;
        bq.x += yx * yx; bq.y += yy * yy; bq.z += yz * yz; bq.w += yw * yw;
    }
    float* rs = &red[wave * 512];
    rs[c4 + 0] = bs.x; rs[c4 + 1] = bs.y; rs[c4 + 2] = bs.z; rs[c4 + 3] = bs.w;
    rs[256 + c4 + 0] = bq.x; rs[256 + c4 + 1] = bq.y;
    rs[256 + c4 + 2] = bq.z; rs[256 + c4 + 3] = bq.w;
    __syncthreads();
    int t = threadIdx.x;
    float v0 = red[t] + red[512 + t] + red[1024 + t] + red[1536 + t];
    float v1 = red[256 + t] + red[768 + t] + red[1280 + t] + red[1792 + t];
    partial[(size_t)blockIdx.x * 512 + t] = v0;
    partial[(size_t)blockIdx.x * 512 + 256 + t] = v1;
}

// combine block partials: 32 blocks, coalesced reads, 32 atomics/address.
__global__ __launch_bounds__(256) void bn_combine(const float* __restrict__ partial,
                                                  float* __restrict__ S) {
    int t = threadIdx.x;
    int b0 = blockIdx.x * (NAGG / 32);
    float s0 = 0.f, s1 = 0.f;
#pragma unroll 8
    for (int b = b0; b < b0 + NAGG / 32; b++) {
        s0 += partial[(size_t)b * 512 + t];
        s1 += partial[(size_t)b * 512 + 256 + t];
    }
    atomicAdd(&S[t], s0);
    atomicAdd(&S[256 + t], s1);
}

// heads=1: final layer, writes fp32 out (keeps bias).
__global__ __launch_bounds__(256) void aggregate_h1(
    const unsigned short* __restrict__ Hb, const float* __restrict__ als,
    const float* __restrict__ ald, const int* __restrict__ offs,
    const int* __restrict__ csr, const float* __restrict__ bias,
    float* __restrict__ Yout, int Nn) {
    int wave = threadIdx.x >> 6;
    int lane = threadIdx.x & 63;
    int sub = lane >> 4, lane16 = lane & 15;
    int n = blockIdx.x * 16 + wave * 4 + sub;
    if (n >= Nn) return;
    int c4 = lane16 * 4;
    float aldn = ald[n];
    int beg = offs[n], end = offs[n + 1];
    float4 acc = make_float4(0.f, 0.f, 0.f, 0.f);
    float den = 0.f;
    for (int b = beg; b < end; b += 16) {
        int cnt = min(16, end - b);
        int idx = 0;
        if (lane16 < cnt) idx = csr[b + lane16];
        int j = 0;
        for (; j + 4 <= cnt; j += 4) {
            int s0 = __shfl(idx, (sub << 4) + j);
            int s1 = __shfl(idx, (sub << 4) + j + 1);
            int s2 = __shfl(idx, (sub << 4) + j + 2);
            int s3 = __shfl(idx, (sub << 4) + j + 3);
            float a0 = als[s0], a1 = als[s1], a2 = als[s2], a3 = als[s3];
            ushort4 h0 = *(const ushort4*)&Hb[(size_t)s0 * 64 + c4];
            ushort4 h1 = *(const ushort4*)&Hb[(size_t)s1 * 64 + c4];
            ushort4 h2 = *(const ushort4*)&Hb[(size_t)s2 * 64 + c4];
            ushort4 h3 = *(const ushort4*)&Hb[(size_t)s3 * 64 + c4];
            float e0 = a0 + aldn; e0 = fmaxf(e0, NEG_ATT * e0);
            float e1 = a1 + aldn; e1 = fmaxf(e1, NEG_ATT * e1);
            float e2 = a2 + aldn; e2 = fmaxf(e2, NEG_ATT * e2);
            float e3 = a3 + aldn; e3 = fmaxf(e3, NEG_ATT * e3);
            float w0 = fexp2(e0), w1 = fexp2(e1), w2 = fexp2(e2), w3 = fexp2(e3);
            den += (w0 + w1) + (w2 + w3);
            acc.x += w0 * b2f(h0.x) + w1 * b2f(h1.x) + w2 * b2f(h2.x) + w3 * b2f(h3.x);
            acc.y += w0 * b2f(h0.y) + w1 * b2f(h1.y) + w2 * b2f(h2.y) + w3 * b2f(h3.y);
            acc.z += w0 * b2f(h0.z) + w1 * b2f(h1.z) + w2 * b2f(h2.z) + w3 * b2f(h3.z);
            acc.w += w0 * b2f(h0.w) + w1 * b2f(h1.w) + w2 * b2f(h2.w) + w3 * b2f(h3.w);
        }
        for (; j < cnt; j++) {
            int s = __shfl(idx, (sub << 4) + j);
            float e = als[s] + aldn;
            e = fmaxf(e, NEG_ATT * e);
            float w = fexp2(e);
            den += w;
            ushort4 hv = *(const ushort4*)&Hb[(size_t)s * 64 + c4];
            acc.x += w * b2f(hv.x); acc.y += w * b2f(hv.y);
            acc.z += w * b2f(hv.z); acc.w += w * b2f(hv.w);
        }
    }
    float inv = 1.f / den;
    float4 bv = *(const float4*)&bias[c4];
    float4 o = make_float4(acc.x * inv + bv.x, acc.y * inv + bv.y,
                           acc.z * inv + bv.z, acc.w * inv + bv.w);
    *(float4*)&Yout[(size_t)n * 64 + c4] = o;
}

// ---------------- BN finalize: scale/shift from fused sums ----------------

__global__ __launch_bounds__(256) void bn_final(
    const float* __restrict__ S, const float* __restrict__ gamma,
    const float* __restrict__ beta, float* __restrict__ scale,
    float* __restrict__ shift, float inv_n) {
    int ch = threadIdx.x;  // 256 channels
    float mu = S[ch] * inv_n;
    float var = S[256 + ch] * inv_n - mu * mu;
    float sc = gamma[ch] * rsqrtf(var + 1e-5f);
    scale[ch] = sc;
    shift[ch] = beta[ch] - mu * sc;
}

// ---------------- launch ----------------

extern "C" void kernel_launch(void* const* d_in, const int* in_sizes, int n_in,
                              void* d_out, int out_size, void* d_ws, size_t ws_size,
                              hipStream_t stream) {
    const float* x    = (const float*)d_in[0];
    const int*   ei   = (const int*)d_in[1];
    const float* W1   = (const float*)d_in[2];
    const float* a1s  = (const float*)d_in[3];
    const float* a1d  = (const float*)d_in[4];
    const float* W2   = (const float*)d_in[6];
    const float* a2s  = (const float*)d_in[7];
    const float* a2d  = (const float*)d_in[8];
    const float* W3   = (const float*)d_in[10];
    const float* a3s  = (const float*)d_in[11];
    const float* a3d  = (const float*)d_in[12];
    const float* b3   = (const float*)d_in[13];
    const float* gamma = (const float*)d_in[14];
    const float* beta  = (const float*)d_in[15];
    float* out = (float*)d_out;

    const int Nn = in_sizes[0] / 128;
    const int E  = in_sizes[1] / 2;
    const int Ep = E + Nn;
    const int Mpad = (Nn + 127) & ~127;

    size_t off = 0;
    char* base = (char*)d_ws;
    auto alloc = [&](size_t bytes) -> void* {
        void* p = base + off;
        off = (off + bytes + 255) & ~(size_t)255;
        return p;
    };
    unsigned short* Hb   = (unsigned short*)alloc((size_t)Mpad * 256 * 2);
    unsigned short* Yb   = (unsigned short*)alloc((size_t)Nn * 256 * 2);
    unsigned short* xb1  = (unsigned short*)alloc((size_t)Mpad * 128 * 2);
    unsigned short* xbig = (unsigned short*)alloc((size_t)Mpad * 256 * 2);
    unsigned short* wb1  = (unsigned short*)alloc((size_t)256 * 128 * 2);
    unsigned short* wb2  = (unsigned short*)alloc((size_t)256 * 256 * 2);
    unsigned short* wb3  = (unsigned short*)alloc((size_t)64 * 256 * 2);
    float* als    = (float*)alloc((size_t)Mpad * 4 * 4);
    float* ald    = (float*)alloc((size_t)Mpad * 4 * 4);
    size_t zoff0 = off;
    int*   deg    = (int*)alloc((size_t)Nn * 4);
    float* sums   = (float*)alloc(1024 * 4);   // 2 layers x (sum[256] | sq[256])
    size_t zbytes = off - zoff0;
    int*   offs   = (int*)alloc((size_t)(Nn + 1) * 4);
    int*   cursor = (int*)alloc((size_t)Nn * 4);
    int*   bsum   = (int*)alloc(64 * 4);
    int*   csr    = (int*)alloc((size_t)Ep * 4);
    float* partial = (float*)alloc((size_t)NAGG * 512 * 4);  // per-block BN partials
    float* scale  = (float*)alloc(256 * 4);
    float* shift  = (float*)alloc(256 * 4);
    (void)ws_size;

    float* sums0 = sums;
    float* sums1 = sums + 512;

    const int G = (Nn + SCAN_CHUNK - 1) / SCAN_CHUNK;

    // ---- deg + BN-sums zero, prep (conversions + edge counting) ----
    hipMemsetAsync(deg, 0, zbytes, stream);
    {
        int nxpad = Mpad * 128;
        int wtot = 256 * 128 + 256 * 256 + 64 * 256;
        int nconv = (nxpad + wtot) / 8;
        prep_all<<<(nconv + E + 255) / 256, 256, 0, stream>>>(
            deg, ei, E, x, xb1, Nn * 128, nxpad,
            W1, wb1, 256 * 128, W2, wb2, 256 * 256, W3, wb3, 64 * 256);
    }

    // ---- CSR build ----
    scan1<<<G, 256, 0, stream>>>(deg, offs, bsum, Nn);
    scan23<<<(Nn + 1 + 255) / 256, 256, 0, stream>>>(offs, bsum, cursor, Nn, G);
    fill_csr<<<(Ep + 255) / 256, 256, 0, stream>>>(ei, cursor, csr, E, Nn);

    const int gm  = Mpad / 128;   // old kernel (h1 layer)
    const int gm4 = Mpad / 64;    // merged-head kernel
    const int nagg1 = (Nn + 15) / 16;
    const float inv_n = 1.f / (float)Nn;

    // ---- Layer 1 ----
    gemm_h4<128, false, false, false><<<gm4, 256, 0, stream>>>(
        xb1, wb1, Hb, a1s, a1d, als, ald, nullptr, nullptr, nullptr, nullptr, Nn);
    aggregate_h4<<<NAGG, 256, 0, stream>>>(Hb, als, ald, offs, csr, Yb, partial, Nn);
    bn_combine<<<32, 256, 0, stream>>>(partial, sums0);
    bn_final<<<1, 256, 0, stream>>>(sums0, gamma, beta, scale, shift, inv_n);

    // ---- Layer 2 (layer-1 BN-apply fused into A-staging; writes xbig once) ----
    gemm_h4<256, true, false, true><<<gm4, 256, 0, stream>>>(
        nullptr, wb2, Hb, a2s, a2d, als, ald, Yb, xbig, scale, shift, Nn);
    aggregate_h4<<<NAGG, 256, 0, stream>>>(Hb, als, ald, offs, csr, Yb, partial, Nn);
    bn_combine<<<32, 256, 0, stream>>>(partial, sums1);
    bn_final<<<1, 256, 0, stream>>>(sums1, gamma, beta, scale, shift, inv_n);

    // ---- Layer 3 (layer-2 BN-apply + residual fused into A-staging) ----
    gemm_mfma<256, 64, 1, true, true, false><<<gm, 256, 0, stream>>>(
        nullptr, wb3, Hb, a3s, a3d, als, ald, Yb, xbig, scale, shift, Nn);
    aggregate_h1<<<nagg1, 256, 0, stream>>>(Hb, als, ald, offs, csr, b3, out, Nn);
}

// Round 8
// 325.123 us; speedup vs baseline: 1.0994x; 1.0994x over previous
//
#include <hip/hip_runtime.h>
#include <hip/hip_bf16.h>

#define NEG_ATT 0.2f
#define NEG_ACT 0.01f
#define LOG2E 1.4426950408889634f

typedef __attribute__((ext_vector_type(8))) short short8;
typedef __attribute__((ext_vector_type(4))) float f32x4;

__device__ __forceinline__ float b2f(unsigned short h) {
    return __uint_as_float((unsigned int)h << 16);
}
// packed f32x2 -> bf16x2 (RNE), single HW instruction on gfx950
__device__ __forceinline__ unsigned cvt_pk_bf16(float lo, float hi) {
    unsigned r;
    asm("v_cvt_pk_bf16_f32 %0, %1, %2" : "=v"(r) : "v"(lo), "v"(hi));
    return r;
}
__device__ __forceinline__ float fexp2(float x) {
#if __has_builtin(__builtin_amdgcn_exp2f)
    return __builtin_amdgcn_exp2f(x);
#else
    return exp2f(x);
#endif
}

// ---------------- CSR build ----------------

#define SCAN_CHUNK 1024
// deg holds edge-counts only (self-loop added as +1 here)
__global__ void scan1(const int* __restrict__ deg, int* __restrict__ offs,
                      int* blocksum, int Nn) {
    __shared__ int sh[256];
    int b = blockIdx.x, t = threadIdx.x;
    int base = b * SCAN_CHUNK + t * 4;
    int v[4];
    int s = 0;
    for (int j = 0; j < 4; j++) {
        int idx = base + j;
        v[j] = (idx < Nn) ? deg[idx] + 1 : 0;
        s += v[j];
    }
    sh[t] = s;
    __syncthreads();
    for (int off = 1; off < 256; off <<= 1) {
        int x = (t >= off) ? sh[t - off] : 0;
        __syncthreads();
        sh[t] += x;
        __syncthreads();
    }
    int excl = sh[t] - s;
    if (t == 255) blocksum[b] = sh[255];
    int run = excl;
    for (int j = 0; j < 4; j++) {
        int idx = base + j;
        if (idx < Nn) offs[idx] = run;
        run += v[j];
    }
}

// fused scan2+scan3: per-thread prefix over <=G block sums (L2-hot)
__global__ void scan23(int* __restrict__ offs, const int* __restrict__ bsum,
                       int* __restrict__ cursor, int Nn, int G) {
    int i = blockIdx.x * 256 + threadIdx.x;
    if (i > Nn) return;
    int g = i >> 10;
    int basev = 0;
    for (int k = 0; k < g; k++) basev += bsum[k];
    if (i == Nn) {
        int tot = basev;
        for (int k = g; k < G; k++) tot += bsum[k];
        offs[Nn] = tot;
        return;
    }
    int v = offs[i] + basev;
    offs[i] = v;
    cursor[i] = v;
}

__global__ void fill_csr(const int* __restrict__ ei, int* cursor, int* csr, int E, int Nn) {
    int t = blockIdx.x * 256 + threadIdx.x;
    if (t < E) {
        int s = ei[t];
        int d = ei[E + t];
        int p = atomicAdd(&cursor[d], 1);
        csr[p] = s;
    } else if (t < E + Nn) {
        int nn = t - E;
        int p = atomicAdd(&cursor[nn], 1);
        csr[p] = nn;
    }
}

// ------- prep: all fp32->bf16 conversions + edge degree count (deg pre-zeroed) -------

__global__ __launch_bounds__(256) void prep_all(
    int* __restrict__ deg, const int* __restrict__ ei, int E,
    const float* __restrict__ x, unsigned short* __restrict__ xb, int nx, int nxpad,
    const float* __restrict__ w1, unsigned short* __restrict__ o1, int n1,
    const float* __restrict__ w2, unsigned short* __restrict__ o2, int n2,
    const float* __restrict__ w3, unsigned short* __restrict__ o3, int n3) {
    int id = blockIdx.x * 256 + threadIdx.x;
    int nconv = (nxpad + n1 + n2 + n3) / 8;
    if (id >= nconv) {
        int e = id - nconv;
        if (e < E) atomicAdd(&deg[ei[E + e]], 1);
        return;
    }
    int i = id * 8;
    const float* in;
    unsigned short* out;
    if (i < nxpad) {
        if (i >= nx) {
            *(ushort4*)&xb[i] = make_ushort4(0, 0, 0, 0);
            *(ushort4*)&xb[i + 4] = make_ushort4(0, 0, 0, 0);
            return;
        }
        in = x + i; out = xb + i;
    } else {
        int j = i - nxpad;
        if (j < n1) { in = w1 + j; out = o1 + j; }
        else if (j < n1 + n2) { in = w2 + (j - n1); out = o2 + (j - n1); }
        else { in = w3 + (j - n1 - n2); out = o3 + (j - n1 - n2); }
    }
    float4 a = *(const float4*)in;
    float4 b = *(const float4*)(in + 4);
    uint4 o;
    o.x = cvt_pk_bf16(a.x, a.y);
    o.y = cvt_pk_bf16(a.z, a.w);
    o.z = cvt_pk_bf16(b.x, b.y);
    o.w = cvt_pk_bf16(b.z, b.w);
    *(uint4*)out = o;
}

// BN-apply transform: leaky(sc*y+sh) (+res when RES), pack 2 bf16 via cvt_pk
template <bool RES>
__device__ __forceinline__ unsigned bnpack2(unsigned short ya, unsigned short yb_,
                                            float sca, float scb, float sha, float shb,
                                            unsigned short ra, unsigned short rb_) {
    float v0 = sca * b2f(ya) + sha; v0 = v0 > 0.f ? v0 : NEG_ACT * v0;
    float v1 = scb * b2f(yb_) + shb; v1 = v1 > 0.f ? v1 : NEG_ACT * v1;
    if (RES) { v0 += b2f(ra); v1 += b2f(rb_); }
    return cvt_pk_bf16(v0, v1);
}

// ---------------- MFMA GEMM (TN) + fused attention-logit epilogue ----------------
// HEADS==4: flat grid gm*4, XCD-aware swizzle (4 head-blocks of an m-tile share an XCD).
// FUSE: A = leaky(scale*Yb_in+shift) [+ RWbuf residual when FRES].
// FWOUT: hd==0 blocks also write the transformed A tile to RWbuf (next residual).
// als/ald are PRE-SCALED by log2(e) so the aggregates can use raw v_exp_f32 (exp2).
// NOTE (r7): merged-head BM=64 variant was a big loss (LDS-capped occupancy 15%,
// grid==capacity single round, B-staging serial) -- per-head structure is the keeper.

template <int K, int CO, int HEADS, bool FUSE, bool FRES, bool FWOUT>
__global__ __launch_bounds__(256) void gemm_mfma(
    const unsigned short* __restrict__ Xb, const unsigned short* __restrict__ Wb,
    unsigned short* __restrict__ Hb, const float* __restrict__ a_s,
    const float* __restrict__ a_d, float* __restrict__ als, float* __restrict__ ald,
    const unsigned short* __restrict__ Yb_in, unsigned short* __restrict__ RWbuf,
    const float* __restrict__ scale, const float* __restrict__ shift, int Nn) {
    constexpr int BM = 128, BK = 64, LD = 72, SLD = 68;
    __shared__ __align__(16) char smem[4 * 32 * SLD * 4];
    unsigned short* As = (unsigned short*)smem;
    unsigned short* Bs = As + BM * LD;
    int tid = threadIdx.x;
    int wave = tid >> 6, lane = tid & 63;
    int quad = lane >> 4, l16 = lane & 15;
    int mt, hd;
    if (HEADS == 4) {
        int gm = gridDim.x >> 2;
        int gm8 = gm & ~7;
        int nfull = gm8 * 4;
        int id = blockIdx.x;
        if (id < nfull) {
            int r = id & 31;
            mt = (id >> 5) * 8 + (r & 7);
            hd = r >> 3;
        } else {
            int t2 = id - nfull;
            mt = gm8 + (t2 >> 2);
            hd = t2 & 3;
        }
    } else {
        mt = blockIdx.x;
        hd = 0;
    }
    int m0 = mt * BM, n0 = hd * 64;
    int arow = tid >> 3;
    int achk = (tid & 7) * 8;
    f32x4 acc[2][4] = {};
    for (int k0 = 0; k0 < K; k0 += BK) {
        __syncthreads();
        if (FUSE) {
            int cb = k0 + achk;
            float4 sc0 = *(const float4*)&scale[cb];
            float4 sc1 = *(const float4*)&scale[cb + 4];
            float4 sh0 = *(const float4*)&shift[cb];
            float4 sh1 = *(const float4*)&shift[cb + 4];
#pragma unroll
            for (int p = 0; p < 4; p++) {
                int r = arow + p * 32;
                int m = m0 + r;
                uint4 o = make_uint4(0, 0, 0, 0);
                if (m < Nn) {
                    ushort4 ua = *(const ushort4*)&Yb_in[(size_t)m * 256 + cb];
                    ushort4 ub = *(const ushort4*)&Yb_in[(size_t)m * 256 + cb + 4];
                    ushort4 ra = make_ushort4(0, 0, 0, 0), rb = ra;
                    if (FRES) {
                        ra = *(const ushort4*)&RWbuf[(size_t)m * 256 + cb];
                        rb = *(const ushort4*)&RWbuf[(size_t)m * 256 + cb + 4];
                    }
                    o.x = bnpack2<FRES>(ua.x, ua.y, sc0.x, sc0.y, sh0.x, sh0.y, ra.x, ra.y);
                    o.y = bnpack2<FRES>(ua.z, ua.w, sc0.z, sc0.w, sh0.z, sh0.w, ra.z, ra.w);
                    o.z = bnpack2<FRES>(ub.x, ub.y, sc1.x, sc1.y, sh1.x, sh1.y, rb.x, rb.y);
                    o.w = bnpack2<FRES>(ub.z, ub.w, sc1.z, sc1.w, sh1.z, sh1.w, rb.z, rb.w);
                    if (FWOUT && hd == 0)
                        *(uint4*)&RWbuf[(size_t)m * 256 + cb] = o;
                }
                *(uint4*)&As[r * LD + achk] = o;
            }
        } else {
#pragma unroll
            for (int p = 0; p < 4; p++) {
                int r = arow + p * 32;
                *(int4*)&As[r * LD + achk] = *(const int4*)&Xb[(size_t)(m0 + r) * K + k0 + achk];
            }
        }
#pragma unroll
        for (int p = 0; p < 2; p++) {
            int r = arow + p * 32;
            *(int4*)&Bs[r * LD + achk] = *(const int4*)&Wb[(size_t)(n0 + r) * K + k0 + achk];
        }
        __syncthreads();
#pragma unroll
        for (int ks = 0; ks < 2; ks++) {
            short8 af[2], bfr[4];
#pragma unroll
            for (int i = 0; i < 2; i++)
                af[i] = *(const short8*)&As[(wave * 32 + i * 16 + l16) * LD + ks * 32 + quad * 8];
#pragma unroll
            for (int j = 0; j < 4; j++)
                bfr[j] = *(const short8*)&Bs[(j * 16 + l16) * LD + ks * 32 + quad * 8];
#pragma unroll
            for (int i = 0; i < 2; i++)
#pragma unroll
                for (int j = 0; j < 4; j++)
                    acc[i][j] = __builtin_amdgcn_mfma_f32_16x16x32_bf16(af[i], bfr[j], acc[i][j], 0, 0, 0);
        }
    }
    __syncthreads();

    float asv[4], adv[4];
#pragma unroll
    for (int j = 0; j < 4; j++) {
        asv[j] = a_s[hd * 64 + j * 16 + l16] * LOG2E;
        adv[j] = a_d[hd * 64 + j * 16 + l16] * LOG2E;
    }
#pragma unroll
    for (int i = 0; i < 2; i++)
#pragma unroll
        for (int r = 0; r < 4; r++) {
            float ps = acc[i][0][r] * asv[0] + acc[i][1][r] * asv[1] +
                       acc[i][2][r] * asv[2] + acc[i][3][r] * asv[3];
            float pd = acc[i][0][r] * adv[0] + acc[i][1][r] * adv[1] +
                       acc[i][2][r] * adv[2] + acc[i][3][r] * adv[3];
#pragma unroll
            for (int mm = 1; mm < 16; mm <<= 1) {
                ps += __shfl_xor(ps, mm);
                pd += __shfl_xor(pd, mm);
            }
            if (l16 == 0) {
                int m = m0 + wave * 32 + i * 16 + quad * 4 + r;
                als[m * HEADS + hd] = ps;
                ald[m * HEADS + hd] = pd;
            }
        }

    float* stg = (float*)smem + wave * 32 * SLD;
#pragma unroll
    for (int i = 0; i < 2; i++)
#pragma unroll
        for (int j = 0; j < 4; j++)
#pragma unroll
            for (int r = 0; r < 4; r++)
                stg[(i * 16 + quad * 4 + r) * SLD + j * 16 + l16] = acc[i][j][r];
    int g = lane >> 3, c8 = (lane & 7) * 8;
#pragma unroll
    for (int p = 0; p < 4; p++) {
        int row = p * 8 + g;
        float4 v0 = *(const float4*)&stg[row * SLD + c8];
        float4 v1 = *(const float4*)&stg[row * SLD + c8 + 4];
        uint4 o;
        o.x = cvt_pk_bf16(v0.x, v0.y);
        o.y = cvt_pk_bf16(v0.z, v0.w);
        o.z = cvt_pk_bf16(v1.x, v1.y);
        o.w = cvt_pk_bf16(v1.z, v1.w);
        *(uint4*)&Hb[(size_t)(m0 + wave * 32 + row) * CO + n0 + c8] = o;
    }
}

// ---------------- edge-softmax aggregation (r0 exact-grid structure) ------------
// One node per wave, exact grid (measured faster than persistent+BN-fused: 39.5 vs
// 48.3 us). readlane-uniform edge walk; exp2 (log2e pre-folded); leaky = max(x,.2x).

#define EDGE4(J)                                                                     \
    {                                                                                \
        int s0 = __builtin_amdgcn_readlane(idx, (J));                                \
        int s1 = __builtin_amdgcn_readlane(idx, (J) + 1);                            \
        int s2 = __builtin_amdgcn_readlane(idx, (J) + 2);                            \
        int s3 = __builtin_amdgcn_readlane(idx, (J) + 3);                            \
        const unsigned short* r0 = Hb + (size_t)s0 * 256;                            \
        const unsigned short* r1 = Hb + (size_t)s1 * 256;                            \
        const unsigned short* r2 = Hb + (size_t)s2 * 256;                            \
        const unsigned short* r3 = Hb + (size_t)s3 * 256;                            \
        float a0 = als[s0 * 4 + hd], a1 = als[s1 * 4 + hd];                          \
        float a2 = als[s2 * 4 + hd], a3 = als[s3 * 4 + hd];                          \
        ushort4 h0 = *(const ushort4*)&r0[c4];                                       \
        ushort4 h1 = *(const ushort4*)&r1[c4];                                       \
        ushort4 h2 = *(const ushort4*)&r2[c4];                                       \
        ushort4 h3 = *(const ushort4*)&r3[c4];                                       \
        float e0 = a0 + aldn; e0 = fmaxf(e0, NEG_ATT * e0);                          \
        float e1 = a1 + aldn; e1 = fmaxf(e1, NEG_ATT * e1);                          \
        float e2 = a2 + aldn; e2 = fmaxf(e2, NEG_ATT * e2);                          \
        float e3 = a3 + aldn; e3 = fmaxf(e3, NEG_ATT * e3);                          \
        float w0 = fexp2(e0), w1 = fexp2(e1), w2 = fexp2(e2), w3 = fexp2(e3);        \
        den += (w0 + w1) + (w2 + w3);                                                \
        acc.x += w0 * b2f(h0.x) + w1 * b2f(h1.x) + w2 * b2f(h2.x) + w3 * b2f(h3.x);  \
        acc.y += w0 * b2f(h0.y) + w1 * b2f(h1.y) + w2 * b2f(h2.y) + w3 * b2f(h3.y);  \
        acc.z += w0 * b2f(h0.z) + w1 * b2f(h1.z) + w2 * b2f(h2.z) + w3 * b2f(h3.z);  \
        acc.w += w0 * b2f(h0.w) + w1 * b2f(h1.w) + w2 * b2f(h2.w) + w3 * b2f(h3.w);  \
    }

__global__ __launch_bounds__(256) void aggregate_h4(
    const unsigned short* __restrict__ Hb, const float* __restrict__ als,
    const float* __restrict__ ald, const int* __restrict__ offs,
    const int* __restrict__ csr, unsigned short* __restrict__ Yb, int Nn) {
    int wave = threadIdx.x >> 6;
    int lane = threadIdx.x & 63;
    int n = blockIdx.x * 4 + wave;
    if (n >= Nn) return;
    int hd = lane >> 4;
    int c4 = lane * 4;
    float aldn = ald[n * 4 + hd];
    int beg = __builtin_amdgcn_readfirstlane(offs[n]);
    int end = __builtin_amdgcn_readfirstlane(offs[n + 1]);
    float4 acc = make_float4(0.f, 0.f, 0.f, 0.f);
    float den = 0.f;
    for (int b = beg; b < end; b += 64) {
        int cnt = min(64, end - b);
        int idx = 0;
        if (lane < cnt) idx = csr[b + lane];
        int j = 0;
        for (; j + 8 <= cnt; j += 8) {
            EDGE4(j);
            EDGE4(j + 4);
        }
        for (; j + 4 <= cnt; j += 4) {
            EDGE4(j);
        }
        for (; j < cnt; j++) {
            int s = __builtin_amdgcn_readlane(idx, j);
            const unsigned short* rr = Hb + (size_t)s * 256;
            float e = als[s * 4 + hd] + aldn;
            e = fmaxf(e, NEG_ATT * e);
            float w = fexp2(e);
            den += w;
            ushort4 hv = *(const ushort4*)&rr[c4];
            acc.x += w * b2f(hv.x); acc.y += w * b2f(hv.y);
            acc.z += w * b2f(hv.z); acc.w += w * b2f(hv.w);
        }
    }
    float inv = 1.f / den;
    uint2 o;
    o.x = cvt_pk_bf16(acc.x * inv, acc.y * inv);
    o.y = cvt_pk_bf16(acc.z * inv, acc.w * inv);
    *(uint2*)&Yb[(size_t)n * 256 + c4] = o;
}

// heads=1: final layer, writes fp32 out (keeps bias).
__global__ __launch_bounds__(256) void aggregate_h1(
    const unsigned short* __restrict__ Hb, const float* __restrict__ als,
    const float* __restrict__ ald, const int* __restrict__ offs,
    const int* __restrict__ csr, const float* __restrict__ bias,
    float* __restrict__ Yout, int Nn) {
    int wave = threadIdx.x >> 6;
    int lane = threadIdx.x & 63;
    int sub = lane >> 4, lane16 = lane & 15;
    int n = blockIdx.x * 16 + wave * 4 + sub;
    if (n >= Nn) return;
    int c4 = lane16 * 4;
    float aldn = ald[n];
    int beg = offs[n], end = offs[n + 1];
    float4 acc = make_float4(0.f, 0.f, 0.f, 0.f);
    float den = 0.f;
    for (int b = beg; b < end; b += 16) {
        int cnt = min(16, end - b);
        int idx = 0;
        if (lane16 < cnt) idx = csr[b + lane16];
        int j = 0;
        for (; j + 4 <= cnt; j += 4) {
            int s0 = __shfl(idx, (sub << 4) + j);
            int s1 = __shfl(idx, (sub << 4) + j + 1);
            int s2 = __shfl(idx, (sub << 4) + j + 2);
            int s3 = __shfl(idx, (sub << 4) + j + 3);
            float a0 = als[s0], a1 = als[s1], a2 = als[s2], a3 = als[s3];
            ushort4 h0 = *(const ushort4*)&Hb[(size_t)s0 * 64 + c4];
            ushort4 h1 = *(const ushort4*)&Hb[(size_t)s1 * 64 + c4];
            ushort4 h2 = *(const ushort4*)&Hb[(size_t)s2 * 64 + c4];
            ushort4 h3 = *(const ushort4*)&Hb[(size_t)s3 * 64 + c4];
            float e0 = a0 + aldn; e0 = fmaxf(e0, NEG_ATT * e0);
            float e1 = a1 + aldn; e1 = fmaxf(e1, NEG_ATT * e1);
            float e2 = a2 + aldn; e2 = fmaxf(e2, NEG_ATT * e2);
            float e3 = a3 + aldn; e3 = fmaxf(e3, NEG_ATT * e3);
            float w0 = fexp2(e0), w1 = fexp2(e1), w2 = fexp2(e2), w3 = fexp2(e3);
            den += (w0 + w1) + (w2 + w3);
            acc.x += w0 * b2f(h0.x) + w1 * b2f(h1.x) + w2 * b2f(h2.x) + w3 * b2f(h3.x);
            acc.y += w0 * b2f(h0.y) + w1 * b2f(h1.y) + w2 * b2f(h2.y) + w3 * b2f(h3.y);
            acc.z += w0 * b2f(h0.z) + w1 * b2f(h1.z) + w2 * b2f(h2.z) + w3 * b2f(h3.z);
            acc.w += w0 * b2f(h0.w) + w1 * b2f(h1.w) + w2 * b2f(h2.w) + w3 * b2f(h3.w);
        }
        for (; j < cnt; j++) {
            int s = __shfl(idx, (sub << 4) + j);
            float e = als[s] + aldn;
            e = fmaxf(e, NEG_ATT * e);
            float w = fexp2(e);
            den += w;
            ushort4 hv = *(const ushort4*)&Hb[(size_t)s * 64 + c4];
            acc.x += w * b2f(hv.x); acc.y += w * b2f(hv.y);
            acc.z += w * b2f(hv.z); acc.w += w * b2f(hv.w);
        }
    }
    float inv = 1.f / den;
    float4 bv = *(const float4*)&bias[c4];
    float4 o = make_float4(acc.x * inv + bv.x, acc.y * inv + bv.y,
                           acc.z * inv + bv.z, acc.w * inv + bv.w);
    *(float4*)&Yout[(size_t)n * 64 + c4] = o;
}

// ---------------- BatchNorm stats over bf16 y (coalesced, 1024 blocks) ----------------

__global__ __launch_bounds__(256) void bn_stats(const unsigned short* __restrict__ Yb,
                                                float* __restrict__ partial, int Nn) {
    __shared__ float red[4 * 512];
    int t = threadIdx.x;
    int g = blockIdx.x;
    int rows_per = (Nn + gridDim.x - 1) / gridDim.x;
    int r0 = g * rows_per;
    int r1 = min(r0 + rows_per, Nn);
    int sub = t >> 6;
    int c4 = (t & 63) * 4;
    float4 s = make_float4(0.f, 0.f, 0.f, 0.f);
    float4 q = make_float4(0.f, 0.f, 0.f, 0.f);
    for (int r = r0 + sub; r < r1; r += 4) {
        ushort4 u = *(const ushort4*)&Yb[(size_t)r * 256 + c4];
        float vx = b2f(u.x), vy = b2f(u.y), vz = b2f(u.z), vw = b2f(u.w);
        s.x += vx; s.y += vy; s.z += vz; s.w += vw;
        q.x += vx * vx; q.y += vy * vy; q.z += vz * vz; q.w += vw * vw;
    }
    float* rs = &red[sub * 512];
    rs[c4 + 0] = s.x; rs[c4 + 1] = s.y; rs[c4 + 2] = s.z; rs[c4 + 3] = s.w;
    rs[256 + c4 + 0] = q.x; rs[256 + c4 + 1] = q.y;
    rs[256 + c4 + 2] = q.z; rs[256 + c4 + 3] = q.w;
    __syncthreads();
    float v0 = red[t] + red[512 + t] + red[1024 + t] + red[1536 + t];
    float v1 = red[256 + t] + red[768 + t] + red[1280 + t] + red[1792 + t];
    partial[(size_t)g * 512 + t] = v0;
    partial[(size_t)g * 512 + 256 + t] = v1;
}

__global__ __launch_bounds__(256) void bn_reduce_final(
    const float* __restrict__ partial, int NP, const float* __restrict__ gamma,
    const float* __restrict__ beta, float* scale, float* shift, int Nn) {
    __shared__ float sh[8];
    int ch = blockIdx.x;
    int t = threadIdx.x;
    int wave = t >> 6, lane = t & 63;
    float s = 0.f, q = 0.f;
    for (int i = t; i < NP; i += 256) {
        s += partial[(size_t)i * 512 + ch];
        q += partial[(size_t)i * 512 + 256 + ch];
    }
    for (int off = 32; off; off >>= 1) {
        s += __shfl_down(s, off);
        q += __shfl_down(q, off);
    }
    if (lane == 0) { sh[wave] = s; sh[4 + wave] = q; }
    __syncthreads();
    if (t == 0) {
        s = sh[0] + sh[1] + sh[2] + sh[3];
        q = sh[4] + sh[5] + sh[6] + sh[7];
        float inv_n = 1.f / (float)Nn;
        float mu = s * inv_n;
        float var = q * inv_n - mu * mu;
        float sc = gamma[ch] * rsqrtf(var + 1e-5f);
        scale[ch] = sc;
        shift[ch] = beta[ch] - mu * sc;
    }
}

// ---------------- launch ----------------

extern "C" void kernel_launch(void* const* d_in, const int* in_sizes, int n_in,
                              void* d_out, int out_size, void* d_ws, size_t ws_size,
                              hipStream_t stream) {
    const float* x    = (const float*)d_in[0];
    const int*   ei   = (const int*)d_in[1];
    const float* W1   = (const float*)d_in[2];
    const float* a1s  = (const float*)d_in[3];
    const float* a1d  = (const float*)d_in[4];
    const float* W2   = (const float*)d_in[6];
    const float* a2s  = (const float*)d_in[7];
    const float* a2d  = (const float*)d_in[8];
    const float* W3   = (const float*)d_in[10];
    const float* a3s  = (const float*)d_in[11];
    const float* a3d  = (const float*)d_in[12];
    const float* b3   = (const float*)d_in[13];
    const float* gamma = (const float*)d_in[14];
    const float* beta  = (const float*)d_in[15];
    float* out = (float*)d_out;

    const int Nn = in_sizes[0] / 128;
    const int E  = in_sizes[1] / 2;
    const int Ep = E + Nn;
    const int Mpad = (Nn + 127) & ~127;

    size_t off = 0;
    char* base = (char*)d_ws;
    auto alloc = [&](size_t bytes) -> void* {
        void* p = base + off;
        off = (off + bytes + 255) & ~(size_t)255;
        return p;
    };
    unsigned short* Hb   = (unsigned short*)alloc((size_t)Mpad * 256 * 2);
    unsigned short* Yb   = (unsigned short*)alloc((size_t)Nn * 256 * 2);
    unsigned short* xb1  = (unsigned short*)alloc((size_t)Mpad * 128 * 2);
    unsigned short* xbig = (unsigned short*)alloc((size_t)Mpad * 256 * 2);
    unsigned short* wb1  = (unsigned short*)alloc((size_t)256 * 128 * 2);
    unsigned short* wb2  = (unsigned short*)alloc((size_t)256 * 256 * 2);
    unsigned short* wb3  = (unsigned short*)alloc((size_t)64 * 256 * 2);
    float* als    = (float*)alloc((size_t)Mpad * 4 * 4);
    float* ald    = (float*)alloc((size_t)Mpad * 4 * 4);
    int*   deg    = (int*)alloc((size_t)Nn * 4);
    int*   offs   = (int*)alloc((size_t)(Nn + 1) * 4);
    int*   cursor = (int*)alloc((size_t)Nn * 4);
    int*   bsum   = (int*)alloc(64 * 4);
    int*   csr    = (int*)alloc((size_t)Ep * 4);
    const int NP = 1024;
    float* partial = (float*)alloc((size_t)NP * 512 * 4);
    float* scale  = (float*)alloc(256 * 4);
    float* shift  = (float*)alloc(256 * 4);
    (void)ws_size;

    const int G = (Nn + SCAN_CHUNK - 1) / SCAN_CHUNK;

    // ---- deg zero + prep (conversions + edge counting) ----
    hipMemsetAsync(deg, 0, (size_t)Nn * 4, stream);
    {
        int nxpad = Mpad * 128;
        int wtot = 256 * 128 + 256 * 256 + 64 * 256;
        int nconv = (nxpad + wtot) / 8;
        prep_all<<<(nconv + E + 255) / 256, 256, 0, stream>>>(
            deg, ei, E, x, xb1, Nn * 128, nxpad,
            W1, wb1, 256 * 128, W2, wb2, 256 * 256, W3, wb3, 64 * 256);
    }

    // ---- CSR build ----
    scan1<<<G, 256, 0, stream>>>(deg, offs, bsum, Nn);
    scan23<<<(Nn + 1 + 255) / 256, 256, 0, stream>>>(offs, bsum, cursor, Nn, G);
    fill_csr<<<(Ep + 255) / 256, 256, 0, stream>>>(ei, cursor, csr, E, Nn);

    const int gm = Mpad / 128;
    const int nagg4 = (Nn + 3) / 4;
    const int nagg1 = (Nn + 15) / 16;

    // ---- Layer 1 ----
    gemm_mfma<128, 256, 4, false, false, false><<<gm * 4, 256, 0, stream>>>(
        xb1, wb1, Hb, a1s, a1d, als, ald, nullptr, nullptr, nullptr, nullptr, 0);
    aggregate_h4<<<nagg4, 256, 0, stream>>>(Hb, als, ald, offs, csr, Yb, Nn);
    bn_stats<<<NP, 256, 0, stream>>>(Yb, partial, Nn);
    bn_reduce_final<<<256, 256, 0, stream>>>(partial, NP, gamma, beta, scale, shift, Nn);

    // ---- Layer 2 (layer-1 BN-apply fused into A-staging; hd==0 writes xbig) ----
    gemm_mfma<256, 256, 4, true, false, true><<<gm * 4, 256, 0, stream>>>(
        nullptr, wb2, Hb, a2s, a2d, als, ald, Yb, xbig, scale, shift, Nn);
    aggregate_h4<<<nagg4, 256, 0, stream>>>(Hb, als, ald, offs, csr, Yb, Nn);
    bn_stats<<<NP, 256, 0, stream>>>(Yb, partial, Nn);
    bn_reduce_final<<<256, 256, 0, stream>>>(partial, NP, gamma, beta, scale, shift, Nn);

    // ---- Layer 3 (layer-2 BN-apply + residual fused into A-staging) ----
    gemm_mfma<256, 64, 1, true, true, false><<<gm, 256, 0, stream>>>(
        nullptr, wb3, Hb, a3s, a3d, als, ald, Yb, xbig, scale, shift, Nn);
    aggregate_h1<<<nagg1, 256, 0, stream>>>(Hb, als, ald, offs, csr, b3, out, Nn);
}